// Round 17
// baseline (51.142 us; speedup 1.0000x reference)
//
#include <hip/hip_runtime.h>
#include <hip/hip_bf16.h>

// out[d,t] = (sum_j exp(s[t,j]) * u[j,d]) / (sum_j exp(s[t,j]))
// Fused exp-GEMM, B staged in LDS once per block.
// R17: 32x32x16 MFMA single-pass — each wave owns 32 t-rows, 8 waves cover
// all 256 rows of the block in ONE pass over K. vs R10: B traversed once
// (not twice), ds_read_b128 count halves, MFMA issue count halves, no panel
// boundary. C/D layout for mfma_f32_32x32x16_bf16 is HW-verified (m74/m101):
// col = lane&31, row = (reg&3) + 8*(reg>>2) + 4*(lane>>5). A/B use the same
// k-map k = kk*32 + ks*16 + (lane>>5)*8 + i (bijective reindex -> K-sum
// invariant). Conservative body: manual f2bf_rne, sched_barrier every iter,
// launch_bounds(512,2) (the only never-spilling class).

constexpr int T_DIM = 65536;
constexpr int J_DIM = 512;
constexpr int D_DIM = 128;
constexpr int KK = 16;                 // K-chunks of 32
constexpr int NFRAG = 4;               // N-fragments of 32 cols (4 x 32 = 128)
constexpr int PF_DEPTH = 4;            // s-load prefetch depth (iterations)
constexpr int BP_ELEMS = KK * 2 * NFRAG * 64;   // 8192 s16x8 = 128KB

typedef __attribute__((ext_vector_type(4)))  float  f32x4;
typedef __attribute__((ext_vector_type(16))) float  f32x16;
typedef __attribute__((ext_vector_type(8)))  short  s16x8;
typedef __attribute__((ext_vector_type(8)))  __bf16 bf16x8;

__device__ __forceinline__ short f2bf_rne(float f) {
    unsigned u = __builtin_bit_cast(unsigned, f);
    u += 0x7fffu + ((u >> 16) & 1u);   // round-to-nearest-even
    return (short)(u >> 16);
}

__global__ __launch_bounds__(512, 2) void c2q_main(const float* __restrict__ sm,
                                                   const float* __restrict__ u,
                                                   float* __restrict__ out) {
    __shared__ s16x8 bsh[BP_ELEMS];    // [kk(16)][ks(2)][nf(4)][lane(64)] — 128KB

    const int tid  = threadIdx.x;
    const int l    = tid & 63;
    const int w    = tid >> 6;        // wave 0..7
    const int l31  = l & 31;
    const int lh5  = l >> 5;          // 0..1
    const int r0w  = blockIdx.x * 256 + w * 32;  // this wave's first t-row

    // A source: lane holds row r0w+l31, k = g*32 + ks*16 + lh5*8 + i.
    const float* sp = sm + (size_t)(r0w + l31) * J_DIM + lh5 * 8;

    // ---- prologue: prefetch iterations 0..3 (4 x 16B per iteration) ----
    f32x4 sbuf[PF_DEPTH][4];
#pragma unroll
    for (int p = 0; p < PF_DEPTH; ++p) {
        sbuf[p][0] = *reinterpret_cast<const f32x4*>(sp + p * 32);
        sbuf[p][1] = *reinterpret_cast<const f32x4*>(sp + p * 32 + 4);
        sbuf[p][2] = *reinterpret_cast<const f32x4*>(sp + p * 32 + 16);
        sbuf[p][3] = *reinterpret_cast<const f32x4*>(sp + p * 32 + 20);
    }

    // ---- B gather-fill from u (L2/L3-resident, 256KB), once per block ----
    // element e: l=e&63, nf=(e>>6)&3, ks=(e>>8)&1, kk=e>>9;
    //   d = nf*32 + (l&31), k0 = kk*32 + ks*16 + (l>>5)*8; pack 8 bf16.
#pragma unroll 4
    for (int it = 0; it < BP_ELEMS / 512; ++it) {
        int e  = it * 512 + tid;
        int d  = ((e >> 6) & 3) * 32 + (e & 31);
        int k0 = (e >> 9) * 32 + ((e >> 8) & 1) * 16 + ((e >> 5) & 1) * 8;
        const float* up = u + (size_t)k0 * D_DIM + d;
        s16x8 o;
#pragma unroll
        for (int i = 0; i < 8; ++i)
            o[i] = f2bf_rne(up[(size_t)i * D_DIM]);
        bsh[e] = o;
    }
    __syncthreads();

    f32x16 acc[NFRAG];
#pragma unroll
    for (int nf = 0; nf < NFRAG; ++nf)
#pragma unroll
        for (int r = 0; r < 16; ++r) acc[nf][r] = 0.f;
    float den = 0.f;

#pragma unroll
    for (int g = 0; g < KK; ++g) {
        const int slot = g & (PF_DEPTH - 1);     // compile-time after unroll
        f32x4 s0 = sbuf[slot][0];
        f32x4 s1 = sbuf[slot][1];
        f32x4 s2 = sbuf[slot][2];
        f32x4 s3 = sbuf[slot][3];
        if (g + PF_DEPTH < KK) {                 // refill for iteration g+4
            const float* b = sp + (g + PF_DEPTH) * 32;
            sbuf[slot][0] = *reinterpret_cast<const f32x4*>(b);
            sbuf[slot][1] = *reinterpret_cast<const f32x4*>(b + 4);
            sbuf[slot][2] = *reinterpret_cast<const f32x4*>(b + 16);
            sbuf[slot][3] = *reinterpret_cast<const f32x4*>(b + 20);
        }
        float e0 = __expf(s0[0]), e1 = __expf(s0[1]);
        float e2 = __expf(s0[2]), e3 = __expf(s0[3]);
        float e4 = __expf(s1[0]), e5 = __expf(s1[1]);
        float e6 = __expf(s1[2]), e7 = __expf(s1[3]);
        float f0 = __expf(s2[0]), f1 = __expf(s2[1]);
        float f2 = __expf(s2[2]), f3 = __expf(s2[3]);
        float f4 = __expf(s3[0]), f5 = __expf(s3[1]);
        float f6 = __expf(s3[2]), f7 = __expf(s3[3]);
        den += ((e0 + e1) + (e2 + e3)) + ((e4 + e5) + (e6 + e7))
             + ((f0 + f1) + (f2 + f3)) + ((f4 + f5) + (f6 + f7));
        s16x8 a0, a1;
        a0[0] = f2bf_rne(e0); a0[1] = f2bf_rne(e1);
        a0[2] = f2bf_rne(e2); a0[3] = f2bf_rne(e3);
        a0[4] = f2bf_rne(e4); a0[5] = f2bf_rne(e5);
        a0[6] = f2bf_rne(e6); a0[7] = f2bf_rne(e7);
        a1[0] = f2bf_rne(f0); a1[1] = f2bf_rne(f1);
        a1[2] = f2bf_rne(f2); a1[3] = f2bf_rne(f3);
        a1[4] = f2bf_rne(f4); a1[5] = f2bf_rne(f5);
        a1[6] = f2bf_rne(f6); a1[7] = f2bf_rne(f7);
        bf16x8 av0 = __builtin_bit_cast(bf16x8, a0);
        bf16x8 av1 = __builtin_bit_cast(bf16x8, a1);
#pragma unroll
        for (int nf = 0; nf < NFRAG; ++nf) {
            bf16x8 b0 = __builtin_bit_cast(bf16x8,
                bsh[((g * 2 + 0) * NFRAG + nf) * 64 + l]);
            acc[nf] = __builtin_amdgcn_mfma_f32_32x32x16_bf16(av0, b0, acc[nf], 0, 0, 0);
            bf16x8 b1 = __builtin_bit_cast(bf16x8,
                bsh[((g * 2 + 1) * NFRAG + nf) * 64 + l]);
            acc[nf] = __builtin_amdgcn_mfma_f32_32x32x16_bf16(av1, b1, acc[nf], 0, 0, 0);
        }
        __builtin_amdgcn_sched_barrier(0);       // fence every iteration
    }

    // den(l) holds row l31's partial over k-half lh5: combine halves.
    den += __shfl_xor(den, 32, 64);
    // C/D layout: col = lane&31 (-> d), row = (reg&3)+8*(reg>>2)+4*(lane>>5).
    // For reg group q (regs 4q..4q+3): rows 8q + 4*lh5 + {0,1,2,3} -> 4
    // consecutive t. den for row r lives in lane r (and r+32).
    float inv[4][4];
#pragma unroll
    for (int q = 0; q < 4; ++q) {
        const int rbase = 8 * q + 4 * lh5;
#pragma unroll
        for (int j = 0; j < 4; ++j)
            inv[q][j] = 1.0f / __shfl(den, rbase + j, 64);
    }

#pragma unroll
    for (int nf = 0; nf < NFRAG; ++nf) {
#pragma unroll
        for (int q = 0; q < 4; ++q) {
            f32x4 v;
#pragma unroll
            for (int j = 0; j < 4; ++j) v[j] = acc[nf][4 * q + j] * inv[q][j];
            *reinterpret_cast<f32x4*>(out + (size_t)(nf * 32 + l31) * T_DIM
                                      + r0w + 8 * q + 4 * lh5) = v;
        }
    }
}

extern "C" void kernel_launch(void* const* d_in, const int* in_sizes, int n_in,
                              void* d_out, int out_size, void* d_ws, size_t ws_size,
                              hipStream_t stream) {
    const float* u = (const float*)d_in[0];   // (1, 512, 128) fp32
    const float* s = (const float*)d_in[1];   // (65536, 512) fp32
    float* out = (float*)d_out;               // (128, 65536) fp32

    c2q_main<<<T_DIM / 256, 512, 0, stream>>>(s, u, out);
}

// Round 18
// 36.035 us; speedup vs baseline: 1.4192x; 1.4192x over previous
//
#include <hip/hip_runtime.h>
#include <hip/hip_bf16.h>

// out[d,t] = (sum_j exp(s[t,j]) * u[j,d]) / (sum_j exp(s[t,j]))
// Fused exp-GEMM, B staged in LDS once per block.
// R18 = R10 verbatim (the session optimum, 36.19us, absmax 0.00390625):
// 256 blocks x 512 threads (1 block/CU), two sequential 128-row panels,
// depth-6 cross-panel rotating register prefetch, fence every 2 iterations,
// v_cvt_pk_bf16_f32 A-pack, B gather-filled from u into 128KB LDS.
// Lesson bank (rounds 5-17): >512-thread blocks, two-tile state, (.,>=4)
// bounds, or 32x32 MFMA acc all trigger allocator spill (VGPR=64/128 +
// WRITE_SIZE inflation); 64KB-LDS 2-block co-residency never materializes
// (R13/R16); in-loop micro-opts are neutral (R15). This configuration is the
// reachable-class optimum: ~85-90% of the structure-adjusted ceiling over the
// ~26.4us compulsory-stream floor.

constexpr int T_DIM = 65536;
constexpr int J_DIM = 512;
constexpr int D_DIM = 128;
constexpr int KK_STEPS = J_DIM / 32;   // 16
constexpr int NFRAG = 8;               // 8 N-fragments covering D=128
constexpr int PF_DEPTH = 6;            // s-load prefetch depth (iterations)
constexpr int BP_ELEMS = KK_STEPS * NFRAG * 64;   // s16x8 elements = 8192 (128KB)

typedef __attribute__((ext_vector_type(4))) float  f32x4;
typedef __attribute__((ext_vector_type(4))) int    i32x4;
typedef __attribute__((ext_vector_type(8))) short  s16x8;
typedef __attribute__((ext_vector_type(8))) __bf16 bf16x8;

__device__ __forceinline__ short f2bf_rne(float f) {
    unsigned u = __builtin_bit_cast(unsigned, f);
    u += 0x7fffu + ((u >> 16) & 1u);   // round-to-nearest-even
    return (short)(u >> 16);
}

__device__ __forceinline__ int cvt_pk_bf16(float lo, float hi) {
    int r;
    asm("v_cvt_pk_bf16_f32 %0, %1, %2" : "=v"(r) : "v"(lo), "v"(hi));
    return r;   // r[15:0]=bf16(lo), r[31:16]=bf16(hi), RNE
}

__global__ __launch_bounds__(512, 2) void c2q_main(const float* __restrict__ sm,
                                                   const float* __restrict__ u,
                                                   float* __restrict__ out) {
    __shared__ s16x8 bsh[BP_ELEMS];    // [kk][nf][lane] — 131072 bytes

    const int tid  = threadIdx.x;
    const int l    = tid & 63;
    const int w    = tid >> 6;        // wave 0..7
    const int lmod = l & 15;
    const int lh   = l >> 4;          // 0..3
    const int r0   = blockIdx.x * 256 + w * 16;  // panel-0 first t-row

    // A-fragment sources: lane holds row r0+lmod, k = kk*32 + 8*lh + i.
    const float* sp0 = sm + (size_t)(r0 + lmod) * J_DIM + lh * 8;
    const float* sp1 = sp0 + 128 * J_DIM;        // panel-1 (r0+128)

    // ---- prologue: prefetch global iterations 0..5 (panel 0, kk 0..5) ----
    f32x4 sbuf[PF_DEPTH][2];
#pragma unroll
    for (int p = 0; p < PF_DEPTH; ++p) {
        sbuf[p][0] = *reinterpret_cast<const f32x4*>(sp0 + p * 32);
        sbuf[p][1] = *reinterpret_cast<const f32x4*>(sp0 + p * 32 + 4);
    }

    // ---- B gather-fill straight from u (L2-resident, 256KB), once ----
#pragma unroll 4
    for (int it = 0; it < BP_ELEMS / 512; ++it) {
        int e  = it * 512 + tid;
        int d  = ((e >> 6) & (NFRAG - 1)) * 16 + (e & 15);
        int k0 = (e >> 9) * 32 + 8 * ((e >> 4) & 3);
        const float* up = u + (size_t)k0 * D_DIM + d;
        s16x8 o;
#pragma unroll
        for (int i = 0; i < 8; ++i)
            o[i] = f2bf_rne(up[(size_t)i * D_DIM]);
        bsh[e] = o;
    }
    __syncthreads();

#pragma unroll
    for (int p = 0; p < 2; ++p) {
        const int rp = r0 + p * 128;

        f32x4 acc[NFRAG];
#pragma unroll
        for (int nf = 0; nf < NFRAG; ++nf) acc[nf] = (f32x4){0.f, 0.f, 0.f, 0.f};
        float den = 0.f;

#pragma unroll
        for (int kk = 0; kk < KK_STEPS; ++kk) {
            const int g    = p * KK_STEPS + kk;      // global iteration 0..31
            const int slot = g % PF_DEPTH;           // compile-time constant
            f32x4 s0 = sbuf[slot][0];
            f32x4 s1 = sbuf[slot][1];
            // refill this slot for global iteration g+6 (possibly next panel)
            if (g + PF_DEPTH < 2 * KK_STEPS) {
                const int   f  = g + PF_DEPTH;
                const float* b = (f < KK_STEPS) ? sp0 : sp1;
                const int   tk = f & (KK_STEPS - 1);
                sbuf[slot][0] = *reinterpret_cast<const f32x4*>(b + tk * 32);
                sbuf[slot][1] = *reinterpret_cast<const f32x4*>(b + tk * 32 + 4);
            }
            float e0 = __expf(s0[0]), e1 = __expf(s0[1]);
            float e2 = __expf(s0[2]), e3 = __expf(s0[3]);
            float e4 = __expf(s1[0]), e5 = __expf(s1[1]);
            float e6 = __expf(s1[2]), e7 = __expf(s1[3]);
            den += ((e0 + e1) + (e2 + e3)) + ((e4 + e5) + (e6 + e7));
            i32x4 aw;
            aw[0] = cvt_pk_bf16(e0, e1);
            aw[1] = cvt_pk_bf16(e2, e3);
            aw[2] = cvt_pk_bf16(e4, e5);
            aw[3] = cvt_pk_bf16(e6, e7);
            bf16x8 av = __builtin_bit_cast(bf16x8, aw);
#pragma unroll
            for (int nf = 0; nf < NFRAG; ++nf) {
                bf16x8 bv = __builtin_bit_cast(bf16x8, bsh[(kk * NFRAG + nf) * 64 + l]);
                acc[nf] = __builtin_amdgcn_mfma_f32_16x16x32_bf16(av, bv, acc[nf], 0, 0, 0);
            }
            if (g & 1) __builtin_amdgcn_sched_barrier(0);  // fence every 2 iters
        }

        // den(l) holds row lmod's partial over k-chunk lh: reduce the 4 chunks.
        den += __shfl_xor(den, 16, 64);
        den += __shfl_xor(den, 32, 64);
        // C/D layout: col = lane&15 (-> d), row = 4*(lane>>4)+reg (-> t).
        float inv[4];
#pragma unroll
        for (int r = 0; r < 4; ++r)
            inv[r] = 1.0f / __shfl(den, 4 * lh + r, 64);

#pragma unroll
        for (int nf = 0; nf < NFRAG; ++nf) {
            f32x4 v;
#pragma unroll
            for (int r = 0; r < 4; ++r) v[r] = acc[nf][r] * inv[r];
            *reinterpret_cast<f32x4*>(out + (size_t)(nf * 16 + lmod) * T_DIM
                                      + rp + 4 * lh) = v;
        }
    }
}

extern "C" void kernel_launch(void* const* d_in, const int* in_sizes, int n_in,
                              void* d_out, int out_size, void* d_ws, size_t ws_size,
                              hipStream_t stream) {
    const float* u = (const float*)d_in[0];   // (1, 512, 128) fp32
    const float* s = (const float*)d_in[1];   // (65536, 512) fp32
    float* out = (float*)d_out;               // (128, 65536) fp32

    c2q_main<<<T_DIM / 256, 512, 0, stream>>>(s, u, out);
}